// Round 4
// baseline (999.158 us; speedup 1.0000x reference)
//
#include <hip/hip_runtime.h>
#include <stdint.h>

#define NN 100000
#define NE 1600000
#define DIM 128
#define BN_EPS 1e-5f
#define NBUCK 391               // ceil(NN/256) col/row buckets of 256 nodes
#define NBLK_GEMM 1563          // ceil(100000/64)
#define NBLK_AGG 6250           // 16 nodes/block: 4 waves x 4 nodes
#define NB_HIST 1024            // grid for grid-strided histogram/scatter kernels
#define CSR_PAD 32              // zero-norm pad records past NE (2-deep prefetch)

typedef unsigned int uint;
typedef unsigned short ushort;
typedef unsigned char uchar;
typedef __attribute__((ext_vector_type(8))) short short8;   // 8 x bf16 (4 VGPRs)
typedef __attribute__((ext_vector_type(4))) float f32x4;
typedef __attribute__((ext_vector_type(2))) float v2f;      // packed fp32 pair

// ---------------- bf16 helpers ----------------

static __device__ __forceinline__ ushort f2bf(float f) {
    uint u = __float_as_uint(f);
    u += 0x7FFF + ((u >> 16) & 1);   // round-to-nearest-even
    return (ushort)(u >> 16);
}
static __device__ __forceinline__ float bf_lo(uint p) { return __uint_as_float(p << 16); }
static __device__ __forceinline__ float bf_hi(uint p) { return __uint_as_float(p & 0xFFFF0000u); }

static __device__ __forceinline__ v2f vfma(v2f a, v2f b, v2f c) {
    return __builtin_elementwise_fma(a, b, c);   // -> v_pk_fma_f32
}
static __device__ __forceinline__ v2f vbc(float s) { v2f r = {s, s}; return r; }

// ============ setup: bucket-sort CSR build (no million-scale atomics) ============
// Grid-strided histogram kernels at NB_HIST blocks (vs 196-391 before):
// the bucket reservation logic only needs each block's edge set to be
// disjoint, which grid-stride partitioning preserves.

__global__ __launch_bounds__(256) void k_count(const int* __restrict__ ei,
                                               const float* __restrict__ x,
                                               int* __restrict__ rowCnt,
                                               int* __restrict__ colCnt,
                                               ushort* __restrict__ xb) {
    __shared__ int hr[NBUCK], hc[NBUCK];
    int tid = threadIdx.x;
    for (int b = tid; b < NBUCK; b += 256) { hr[b] = 0; hc[b] = 0; }
    __syncthreads();
    const int gstep = NB_HIST * 256;
    const int gt = blockIdx.x * 256 + tid;
    for (int e = gt; e < NE; e += gstep) {
        atomicAdd(&hr[ei[e] >> 8], 1);
        atomicAdd(&hc[ei[NE + e] >> 8], 1);
    }
    __syncthreads();
    for (int b = tid; b < NBUCK; b += 256) {
        if (hr[b]) atomicAdd(&rowCnt[b], hr[b]);
        if (hc[b]) atomicAdd(&colCnt[b], hc[b]);
    }
    // fused fp32 -> bf16 convert of x (independent work, saves a launch)
    for (int i = gt; i < NN * DIM / 4; i += gstep) {
        float4 v = ((const float4*)x)[i];
        ushort4 o = {f2bf(v.x), f2bf(v.y), f2bf(v.z), f2bf(v.w)};
        ((ushort4*)xb)[i] = o;
    }
}

__global__ __launch_bounds__(512) void k_scanb(const int* __restrict__ rowCnt,
                                               const int* __restrict__ colCnt,
                                               int* __restrict__ rowBase,
                                               int* __restrict__ colBase,
                                               int* __restrict__ rowCur,
                                               int* __restrict__ colCur) {
    __shared__ int s[512];
    int tid = threadIdx.x;
    int v = (tid < NBUCK) ? rowCnt[tid] : 0;
    s[tid] = v;
    __syncthreads();
    for (int d = 1; d < 512; d <<= 1) {
        int a = (tid >= d) ? s[tid - d] : 0;
        __syncthreads();
        s[tid] += a;
        __syncthreads();
    }
    if (tid < NBUCK) { int e = s[tid] - v; rowBase[tid] = e; rowCur[tid] = e; }
    if (tid == NBUCK) rowBase[NBUCK] = s[NBUCK];
    __syncthreads();
    v = (tid < NBUCK) ? colCnt[tid] : 0;
    s[tid] = v;
    __syncthreads();
    for (int d = 1; d < 512; d <<= 1) {
        int a = (tid >= d) ? s[tid - d] : 0;
        __syncthreads();
        s[tid] += a;
        __syncthreads();
    }
    if (tid < NBUCK) { int e = s[tid] - v; colBase[tid] = e; colCur[tid] = e; }
    if (tid == NBUCK) colBase[NBUCK] = s[NBUCK];
}

__global__ __launch_bounds__(256) void k_scat_row(const int* __restrict__ ei,
                                                  int* __restrict__ rowCur,
                                                  uchar* __restrict__ rowScat) {
    __shared__ int h[NBUCK], lb[NBUCK], lc[NBUCK];
    int tid = threadIdx.x;
    for (int b = tid; b < NBUCK; b += 256) { h[b] = 0; lc[b] = 0; }
    __syncthreads();
    const int gstep = NB_HIST * 256;
    const int gt = blockIdx.x * 256 + tid;
    for (int e = gt; e < NE; e += gstep) atomicAdd(&h[ei[e] >> 8], 1);
    __syncthreads();
    for (int b = tid; b < NBUCK; b += 256)
        lb[b] = h[b] ? atomicAdd(&rowCur[b], h[b]) : 0;
    __syncthreads();
    for (int e = gt; e < NE; e += gstep) {
        int r = ei[e];
        int b = r >> 8;
        int pos = lb[b] + atomicAdd(&lc[b], 1);
        rowScat[pos] = (uchar)(r & 255);
    }
}

__global__ __launch_bounds__(1024) void k_deg(const uchar* __restrict__ rowScat,
                                              const int* __restrict__ rowBase,
                                              float* __restrict__ dinv) {
    __shared__ int h[256];
    int tid = threadIdx.x;
    int b = blockIdx.x;
    if (tid < 256) h[tid] = 0;
    __syncthreads();
    int base = rowBase[b], cnt = rowBase[b + 1] - base;
    for (int i = tid; i < cnt; i += 1024) atomicAdd(&h[rowScat[base + i]], 1);
    __syncthreads();
    if (tid < 256) {
        int node = b * 256 + tid;
        if (node < NN) dinv[node] = rsqrtf((float)h[tid] + 1.0f);
    }
}

// record: {norm, bf16(ea0)|bf16(ea1), bf16(ea2)|fine8, row}
__global__ __launch_bounds__(256) void k_scat_col(const int* __restrict__ ei,
                                                  const float* __restrict__ ea,
                                                  const float* __restrict__ dinv,
                                                  int* __restrict__ colCur,
                                                  uint4* __restrict__ tmp) {
    __shared__ int h[NBUCK], lb[NBUCK], lc[NBUCK];
    int tid = threadIdx.x;
    for (int b = tid; b < NBUCK; b += 256) { h[b] = 0; lc[b] = 0; }
    __syncthreads();
    const int gstep = NB_HIST * 256;
    const int gt = blockIdx.x * 256 + tid;
    for (int e = gt; e < NE; e += gstep) atomicAdd(&h[ei[NE + e] >> 8], 1);
    __syncthreads();
    for (int b = tid; b < NBUCK; b += 256)
        lb[b] = h[b] ? atomicAdd(&colCur[b], h[b]) : 0;
    __syncthreads();
    for (int e = gt; e < NE; e += gstep) {
        int r = ei[e];
        int c = ei[NE + e];
        int b = c >> 8;
        int pos = lb[b] + atomicAdd(&lc[b], 1);
        uint4 rec;
        rec.x = __float_as_uint(dinv[r] * dinv[c]);
        rec.y = ((uint)f2bf(ea[e * 3]) << 16) | (uint)f2bf(ea[e * 3 + 1]);
        rec.z = ((uint)f2bf(ea[e * 3 + 2]) << 16) | (uint)(c & 255);
        rec.w = (uint)r;
        tmp[pos] = rec;
    }
}

__global__ __launch_bounds__(1024) void k_sort_col(const uint4* __restrict__ tmp,
                                                   const int* __restrict__ colBase,
                                                   uint4* __restrict__ csr,
                                                   int* __restrict__ offs) {
    __shared__ int hh[256], sc[256], cur[256];
    int tid = threadIdx.x;
    int b = blockIdx.x;
    if (tid < 256) hh[tid] = 0;
    __syncthreads();
    int base = colBase[b], cnt = colBase[b + 1] - base;
    for (int i = tid; i < cnt; i += 1024) atomicAdd(&hh[tmp[base + i].z & 255], 1);
    __syncthreads();
    int v = 0;
    if (tid < 256) { v = hh[tid]; sc[tid] = v; }
    __syncthreads();
    for (int d = 1; d < 256; d <<= 1) {
        int add = 0;
        if (tid < 256 && tid >= d) add = sc[tid - d];
        __syncthreads();
        if (tid < 256) sc[tid] += add;
        __syncthreads();
    }
    if (tid < 256) {
        int excl = sc[tid] - v;
        int node = b * 256 + tid;
        if (node < NN) offs[node] = base + excl;
        if (b == NBUCK - 1 && tid == 0) offs[NN] = NE;
        cur[tid] = excl;
    }
    __syncthreads();
    for (int i = tid; i < cnt; i += 1024) {
        uint4 rec = tmp[base + i];
        int f = rec.z & 255;
        int pos = atomicAdd(&cur[f], 1);
        csr[base + pos] = rec;
    }
}

// ---------------- fused BN-fold + weight prep ----------------
// grid 256 x 128. Blocks 0..127: Wt row n (bf16, transposed, A-scaled).
// Blocks 128..255: beff col j + zero snext stats.
// mode==0: identity BN (first layer); else A/B from sprev stats.

__global__ __launch_bounds__(128) void k_prep(const float* __restrict__ W,
                                              const float* __restrict__ b,
                                              const float* __restrict__ g,
                                              const float* __restrict__ bt,
                                              const float* __restrict__ sprev,
                                              float* __restrict__ snext,
                                              int mode,
                                              ushort* __restrict__ Wt,
                                              float* __restrict__ beff) {
    __shared__ float s[DIM];
    int k = threadIdx.x;
    float A = 1.0f, B = 0.0f;
    if (mode) {
        float m = sprev[k] * (1.0f / NN);
        float var = sprev[DIM + k] * (1.0f / NN) - m * m;
        float rs = rsqrtf(var + BN_EPS);
        A = rs * g[k];
        B = bt[k] - m * A;
    }
    if (blockIdx.x < DIM) {
        int n = blockIdx.x;
        Wt[n * DIM + k] = f2bf(A * W[k * DIM + n]);
    } else {
        int j = blockIdx.x - DIM;
        s[k] = B * W[k * DIM + j];
        __syncthreads();
        for (int d = 64; d > 0; d >>= 1) {
            if (k < d) s[k] += s[k + d];
            __syncthreads();
        }
        if (k == 0) {
            beff[j] = b[j] + s[0];
            snext[j] = 0.0f;
            snext[DIM + j] = 0.0f;
        }
    }
}

// ---------------- MFMA GEMM: Y[M,128] = A_bf[M,128] @ W + beff ----------------
// C/D: col = lane&15, row = quad*4 + reg  [measured: learn_hip m89/m91]

#define GEMM_MFMA_BODY(Abf, Wt)                                                     \
    const int lane = threadIdx.x & 63;                                              \
    const int wv   = threadIdx.x >> 6;                                              \
    const int m    = lane & 15;                                                     \
    const int quad = lane >> 4;                                                     \
    const int row0 = blockIdx.x * 64 + wv * 16;                                     \
    const int rr   = min(row0 + m, NN - 1);                                         \
    const short8* ap = (const short8*)&Abf[(size_t)rr * DIM + quad * 8];            \
    short8 a0 = ap[0];                                                              \
    short8 a1 = ap[4];                                                              \
    short8 a2 = ap[8];                                                              \
    short8 a3 = ap[12];                                                             \
    f32x4 acc[8];                                                                   \
    _Pragma("unroll")                                                               \
    for (int nt = 0; nt < 8; ++nt) {                                                \
        const short8* bp = (const short8*)&Wt[(size_t)(nt * 16 + m) * DIM + quad * 8]; \
        f32x4 c = {0.f, 0.f, 0.f, 0.f};                                             \
        c = __builtin_amdgcn_mfma_f32_16x16x32_bf16(a0, bp[0],  c, 0, 0, 0);        \
        c = __builtin_amdgcn_mfma_f32_16x16x32_bf16(a1, bp[4],  c, 0, 0, 0);        \
        c = __builtin_amdgcn_mfma_f32_16x16x32_bf16(a2, bp[8],  c, 0, 0, 0);        \
        c = __builtin_amdgcn_mfma_f32_16x16x32_bf16(a3, bp[12], c, 0, 0, 0);        \
        acc[nt] = c;                                                                \
    }                                                                               \
    const int rbase = row0 + quad * 4;

__global__ __launch_bounds__(256) void k_gemm_mf_bf(const ushort* __restrict__ Abf,
                                                    const ushort* __restrict__ Wt,
                                                    const float* __restrict__ beff,
                                                    ushort* __restrict__ Y) {
    GEMM_MFMA_BODY(Abf, Wt)
#pragma unroll
    for (int nt = 0; nt < 8; ++nt) {
        int col = nt * 16 + m;
        float bb = beff[col];
#pragma unroll
        for (int i = 0; i < 4; ++i) {
            int row = rbase + i;
            if (row < NN) Y[(size_t)row * DIM + col] = f2bf(acc[nt][i] + bb);
        }
    }
}

__global__ __launch_bounds__(256) void k_gemm_mf_f32(const ushort* __restrict__ Abf,
                                                     const ushort* __restrict__ Wt,
                                                     const float* __restrict__ beff,
                                                     float* __restrict__ Y) {
    GEMM_MFMA_BODY(Abf, Wt)
#pragma unroll
    for (int nt = 0; nt < 8; ++nt) {
        int col = nt * 16 + m;
        float bb = beff[col];
#pragma unroll
        for (int i = 0; i < 4; ++i) {
            int row = rbase + i;
            if (row < NN) Y[(size_t)row * DIM + col] = acc[nt][i] + bb;
        }
    }
}

// ---------------- aggregation + fused BN statistics ----------------
// wave processes 4 nodes; 8 edges/iter (lane = q*16 + oc, 4 edge-quads x 2).
// 2-deep software pipeline: csr records prefetched 1 iter ahead, h gathers
// issued 1 iter ahead of use. BN partials merged per block in LDS, then one
// atomicAdd per thread directly into the (prep-zeroed) stats buffer.

static __device__ __forceinline__ void edge_compute(float4 r, float4 hv, float n,
                                                    const v2f* __restrict__ w0,
                                                    const v2f* __restrict__ w1,
                                                    const v2f* __restrict__ w2,
                                                    const v2f* __restrict__ vbe,
                                                    v2f* __restrict__ acc) {
    uint py = __float_as_uint(r.y), pz = __float_as_uint(r.z);
    v2f va0 = vbc(bf_hi(py)), va1 = vbc(bf_lo(py)), va2 = vbc(bf_hi(pz));
    v2f vn = vbc(n);
    uint hx = __float_as_uint(hv.x), hy = __float_as_uint(hv.y);
    uint hz = __float_as_uint(hv.z), hw = __float_as_uint(hv.w);
    v2f hp[4] = {{bf_lo(hx), bf_hi(hx)}, {bf_lo(hy), bf_hi(hy)},
                 {bf_lo(hz), bf_hi(hz)}, {bf_lo(hw), bf_hi(hw)}};
    const v2f z = {0.0f, 0.0f};
#pragma unroll
    for (int j = 0; j < 4; ++j) {
        v2f e = vfma(va2, w2[j], vbe[j]);
        e = vfma(va1, w1[j], e);
        e = vfma(va0, w0[j], e);
        v2f u = hp[j] + e;
        u = __builtin_elementwise_max(u, z);   // v_pk_max_f32
        acc[j] = vfma(vn, u, acc[j]);
    }
}

__global__ __launch_bounds__(256) void k_agg(const float4* __restrict__ h4,
                                             const float4* __restrict__ csr,
                                             const int* __restrict__ offs,
                                             const float* __restrict__ We,
                                             const float* __restrict__ be,
                                             uint* __restrict__ tb,
                                             float* __restrict__ stats) {
    __shared__ float pbuf[4][256];
    int wv = threadIdx.x >> 6;
    int lane = threadIdx.x & 63;
    int q  = lane >> 4;
    int oc = lane & 15;
    int j0 = oc * 8;

    float4 t0, t1;
    t0 = *(const float4*)&We[j0];             t1 = *(const float4*)&We[j0 + 4];
    v2f w0[4] = {{t0.x, t0.y}, {t0.z, t0.w}, {t1.x, t1.y}, {t1.z, t1.w}};
    t0 = *(const float4*)&We[DIM + j0];       t1 = *(const float4*)&We[DIM + j0 + 4];
    v2f w1[4] = {{t0.x, t0.y}, {t0.z, t0.w}, {t1.x, t1.y}, {t1.z, t1.w}};
    t0 = *(const float4*)&We[2 * DIM + j0];   t1 = *(const float4*)&We[2 * DIM + j0 + 4];
    v2f w2[4] = {{t0.x, t0.y}, {t0.z, t0.w}, {t1.x, t1.y}, {t1.z, t1.w}};
    t0 = *(const float4*)&be[j0];             t1 = *(const float4*)&be[j0 + 4];
    v2f vbe[4] = {{t0.x, t0.y}, {t0.z, t0.w}, {t1.x, t1.y}, {t1.z, t1.w}};

    v2f smv[4] = {{0,0},{0,0},{0,0},{0,0}};
    v2f sqv[4] = {{0,0},{0,0},{0,0},{0,0}};

    const int v0 = blockIdx.x * 16 + wv * 4;     // NBLK_AGG*16 == NN exactly
    int ofs[5];
#pragma unroll
    for (int k = 0; k < 5; ++k) ofs[k] = offs[v0 + k];

    for (int it = 0; it < 4; ++it) {
        int v = v0 + it;
        v2f acc[4] = {{0,0},{0,0},{0,0},{0,0}};
        int s0 = ofs[it], e0 = ofs[it + 1];

        // pipeline prologue: issue csr for iter0 AND iter1 together, then
        // h gathers for iter0 (rA wait is the only exposed latency per node)
        float4 rA1 = csr[s0 + q];
        float4 rA2 = csr[s0 + 4 + q];
        float4 rB1 = csr[s0 + 8 + q];
        float4 rB2 = csr[s0 + 12 + q];
        float4 hA1 = h4[(size_t)__float_as_int(rA1.w) * 16 + oc];
        float4 hA2 = h4[(size_t)__float_as_int(rA2.w) * 16 + oc];

#pragma unroll 2
        for (int base = s0; base < e0; base += 8) {
            // stage B: rows -> issue h(B); issue csr(C)
            float4 hB1 = h4[(size_t)__float_as_int(rB1.w) * 16 + oc];
            float4 hB2 = h4[(size_t)__float_as_int(rB2.w) * 16 + oc];
            float4 rC1 = csr[base + 16 + q];
            float4 rC2 = csr[base + 20 + q];
            // stage A compute (hA issued one iteration ago)
            float n1 = (base + q < e0) ? rA1.x : 0.0f;
            float n2 = (base + 4 + q < e0) ? rA2.x : 0.0f;
            edge_compute(rA1, hA1, n1, w0, w1, w2, vbe, acc);
            edge_compute(rA2, hA2, n2, w0, w1, w2, vbe, acc);
            rA1 = rB1; rA2 = rB2; rB1 = rC1; rB2 = rC2;
            hA1 = hB1; hA2 = hB2;
        }

        // reduce across the 4 edge-quads (lanes with equal oc)
#pragma unroll
        for (int j = 0; j < 4; ++j) {
            acc[j].x += __shfl_xor(acc[j].x, 16); acc[j].x += __shfl_xor(acc[j].x, 32);
            acc[j].y += __shfl_xor(acc[j].y, 16); acc[j].y += __shfl_xor(acc[j].y, 32);
        }

        if (q == 0) {
            uint4 pk;
            uint pw[4];
#pragma unroll
            for (int j = 0; j < 4; ++j) {
                acc[j].x = fmaxf(acc[j].x, 0.0f);   // outer relu
                acc[j].y = fmaxf(acc[j].y, 0.0f);
                smv[j] = smv[j] + acc[j];
                sqv[j] = vfma(acc[j], acc[j], sqv[j]);
                pw[j] = ((uint)f2bf(acc[j].y) << 16) | f2bf(acc[j].x);
            }
            pk.x = pw[0]; pk.y = pw[1]; pk.z = pw[2]; pk.w = pw[3];
            *(uint4*)&tb[(size_t)v * 64 + oc * 4] = pk;
        }
    }

    if (q == 0) {
#pragma unroll
        for (int j = 0; j < 4; ++j) {
            pbuf[wv][j0 + 2 * j]       = smv[j].x;
            pbuf[wv][j0 + 2 * j + 1]   = smv[j].y;
            pbuf[wv][128 + j0 + 2 * j]     = sqv[j].x;
            pbuf[wv][128 + j0 + 2 * j + 1] = sqv[j].y;
        }
    }
    __syncthreads();
    int tid = threadIdx.x;
    float s = pbuf[0][tid] + pbuf[1][tid] + pbuf[2][tid] + pbuf[3][tid];
    atomicAdd(&stats[tid], s);
}

// ---------------- launch ----------------

static inline char* alignp(char* p, size_t a) {
    return (char*)(((uintptr_t)p + a - 1) & ~(uintptr_t)(a - 1));
}

extern "C" void kernel_launch(void* const* d_in, const int* in_sizes, int n_in,
                              void* d_out, int out_size, void* d_ws, size_t ws_size,
                              hipStream_t stream) {
    const float* x   = (const float*)d_in[0];
    const int*   ei  = (const int*)d_in[1];
    const float* ea  = (const float*)d_in[2];
    const float* Wp[3]  = {(const float*)d_in[3],  (const float*)d_in[9],  (const float*)d_in[15]};
    const float* bp[3]  = {(const float*)d_in[4],  (const float*)d_in[10], (const float*)d_in[16]};
    const float* Wep[3] = {(const float*)d_in[5],  (const float*)d_in[11], (const float*)d_in[17]};
    const float* bep[3] = {(const float*)d_in[6],  (const float*)d_in[12], (const float*)d_in[18]};
    const float* gp[3]  = {(const float*)d_in[7],  (const float*)d_in[13], (const float*)d_in[19]};
    const float* btp[3] = {(const float*)d_in[8],  (const float*)d_in[14], (const float*)d_in[20]};
    const float* Wl  = (const float*)d_in[21];
    const float* bl  = (const float*)d_in[22];
    float* out = (float*)d_out;

    char* p = (char*)d_ws;
    auto alloc = [&](size_t bytes) -> void* {
        p = alignp(p, 256);
        void* r = (void*)p;
        p += bytes;
        return r;
    };

    int*    bcnt     = (int*)alloc(2 * NBUCK * sizeof(int));
    int*    rowCnt   = bcnt;
    int*    colCnt   = bcnt + NBUCK;
    int*    rowBase  = (int*)alloc((NBUCK + 1) * sizeof(int));
    int*    colBase  = (int*)alloc((NBUCK + 1) * sizeof(int));
    int*    rowCur   = (int*)alloc(NBUCK * sizeof(int));
    int*    colCur   = (int*)alloc(NBUCK * sizeof(int));
    int*    offs     = (int*)alloc((NN + 1) * sizeof(int));
    float*  dinv     = (float*)alloc(NN * sizeof(float));
    uchar*  rowScat  = (uchar*)alloc(NE * sizeof(uchar));
    uint4*  csr      = (uint4*)alloc(((size_t)NE + CSR_PAD) * sizeof(uint4));
    ushort* x_bf     = (ushort*)alloc((size_t)NN * DIM * sizeof(ushort));
    ushort* h_bf     = (ushort*)alloc((size_t)NN * DIM * sizeof(ushort));
    ushort* t_bf     = (ushort*)alloc((size_t)NN * DIM * sizeof(ushort));
    ushort* Wt       = (ushort*)alloc(DIM * DIM * sizeof(ushort));
    float*  beff     = (float*)alloc(DIM * sizeof(float));
    float*  sb0      = (float*)alloc(2 * DIM * sizeof(float));
    float*  sb1      = (float*)alloc(2 * DIM * sizeof(float));

    // tmp (bucket-scattered records) aliases t_bf: both 25.6 MB; tmp dies at
    // k_sort_col, t_bf is first written by layer-1 k_agg (strictly later).
    uint4* tmp = (uint4*)t_bf;

    hipMemsetAsync(bcnt, 0, 2 * NBUCK * sizeof(int), stream);
    hipMemsetAsync(csr + NE, 0, CSR_PAD * sizeof(uint4), stream);  // zero-norm pad
    k_count<<<NB_HIST, 256, 0, stream>>>(ei, x, rowCnt, colCnt, x_bf);
    k_scanb<<<1, 512, 0, stream>>>(rowCnt, colCnt, rowBase, colBase, rowCur, colCur);
    k_scat_row<<<NB_HIST, 256, 0, stream>>>(ei, rowCur, rowScat);
    k_deg<<<NBUCK, 1024, 0, stream>>>(rowScat, rowBase, dinv);
    k_scat_col<<<NB_HIST, 256, 0, stream>>>(ei, ea, dinv, colCur, tmp);
    k_sort_col<<<NBUCK, 1024, 0, stream>>>(tmp, colBase, csr, offs);

    // stats double-buffer: scur(l) = (l&1)? sb1 : sb0; sprev(l) = the other.
    float* sbs[2] = {sb0, sb1};
    const ushort* Xbf = x_bf;
    for (int l = 0; l < 3; ++l) {
        float* scur = sbs[l & 1];
        float* sprev = sbs[(l + 1) & 1];
        const float* gg = (l == 0) ? gp[0] : gp[l - 1];
        const float* bb = (l == 0) ? btp[0] : btp[l - 1];
        k_prep<<<256, 128, 0, stream>>>(Wp[l], bp[l], gg, bb, sprev, scur,
                                        (l == 0) ? 0 : 1, Wt, beff);
        k_gemm_mf_bf<<<NBLK_GEMM, 256, 0, stream>>>(Xbf, Wt, beff, h_bf);
        k_agg<<<NBLK_AGG, 256, 0, stream>>>((const float4*)h_bf, (const float4*)csr, offs,
                                            Wep[l], bep[l], (uint*)t_bf, scur);
        Xbf = t_bf;
    }

    // final linear: BN3 folded (stats in scur(2) = sb0)
    k_prep<<<256, 128, 0, stream>>>(Wl, bl, gp[2], btp[2], sb0, sb1, 1, Wt, beff);
    k_gemm_mf_f32<<<NBLK_GEMM, 256, 0, stream>>>(t_bf, Wt, beff, out);
}

// Round 7
// 747.205 us; speedup vs baseline: 1.3372x; 1.3372x over previous
//
#include <hip/hip_runtime.h>
#include <stdint.h>

#define NN 100000
#define NE 1600000
#define DIM 128
#define BN_EPS 1e-5f
#define NBUCK 391               // ceil(NN/256) col/row buckets of 256 nodes
#define NBLK_GEMM 1563          // ceil(100000/64)
#define NBLK_AGG 6250           // 16 nodes/block: 4 waves x 4 nodes
#define NB_HIST 1024            // grid for grid-strided histogram/scatter kernels
#define CSR_PAD 32              // zero-norm pad records past NE (2-deep prefetch)
#define NREP 64                 // stats replica slots (contention: 6250/64 ~= 98 per addr)

typedef unsigned int uint;
typedef unsigned short ushort;
typedef unsigned char uchar;
typedef __attribute__((ext_vector_type(8))) short short8;   // 8 x bf16 (4 VGPRs)
typedef __attribute__((ext_vector_type(4))) float f32x4;
typedef __attribute__((ext_vector_type(2))) float v2f;      // packed fp32 pair

// ---------------- bf16 helpers ----------------

static __device__ __forceinline__ ushort f2bf(float f) {
    uint u = __float_as_uint(f);
    u += 0x7FFF + ((u >> 16) & 1);   // round-to-nearest-even
    return (ushort)(u >> 16);
}
static __device__ __forceinline__ float bf_lo(uint p) { return __uint_as_float(p << 16); }
static __device__ __forceinline__ float bf_hi(uint p) { return __uint_as_float(p & 0xFFFF0000u); }

static __device__ __forceinline__ v2f vfma(v2f a, v2f b, v2f c) {
    return __builtin_elementwise_fma(a, b, c);   // -> v_pk_fma_f32
}
static __device__ __forceinline__ v2f vbc(float s) { v2f r = {s, s}; return r; }

// ============ setup: bucket-sort CSR build (no million-scale atomics) ============
// Grid-strided histogram kernels at NB_HIST blocks: bucket reservation only
// needs each block's edge set disjoint, which grid-stride preserves.

__global__ __launch_bounds__(256) void k_count(const int* __restrict__ ei,
                                               const float* __restrict__ x,
                                               int* __restrict__ rowCnt,
                                               int* __restrict__ colCnt,
                                               ushort* __restrict__ xb) {
    __shared__ int hr[NBUCK], hc[NBUCK];
    int tid = threadIdx.x;
    for (int b = tid; b < NBUCK; b += 256) { hr[b] = 0; hc[b] = 0; }
    __syncthreads();
    const int gstep = NB_HIST * 256;
    const int gt = blockIdx.x * 256 + tid;
    for (int e = gt; e < NE; e += gstep) {
        atomicAdd(&hr[ei[e] >> 8], 1);
        atomicAdd(&hc[ei[NE + e] >> 8], 1);
    }
    __syncthreads();
    for (int b = tid; b < NBUCK; b += 256) {
        if (hr[b]) atomicAdd(&rowCnt[b], hr[b]);
        if (hc[b]) atomicAdd(&colCnt[b], hc[b]);
    }
    // fused fp32 -> bf16 convert of x (independent work, saves a launch)
    for (int i = gt; i < NN * DIM / 4; i += gstep) {
        float4 v = ((const float4*)x)[i];
        ushort4 o = {f2bf(v.x), f2bf(v.y), f2bf(v.z), f2bf(v.w)};
        ((ushort4*)xb)[i] = o;
    }
}

__global__ __launch_bounds__(512) void k_scanb(const int* __restrict__ rowCnt,
                                               const int* __restrict__ colCnt,
                                               int* __restrict__ rowBase,
                                               int* __restrict__ colBase,
                                               int* __restrict__ rowCur,
                                               int* __restrict__ colCur) {
    __shared__ int s[512];
    int tid = threadIdx.x;
    int v = (tid < NBUCK) ? rowCnt[tid] : 0;
    s[tid] = v;
    __syncthreads();
    for (int d = 1; d < 512; d <<= 1) {
        int a = (tid >= d) ? s[tid - d] : 0;
        __syncthreads();
        s[tid] += a;
        __syncthreads();
    }
    if (tid < NBUCK) { int e = s[tid] - v; rowBase[tid] = e; rowCur[tid] = e; }
    if (tid == NBUCK) rowBase[NBUCK] = s[NBUCK];
    __syncthreads();
    v = (tid < NBUCK) ? colCnt[tid] : 0;
    s[tid] = v;
    __syncthreads();
    for (int d = 1; d < 512; d <<= 1) {
        int a = (tid >= d) ? s[tid - d] : 0;
        __syncthreads();
        s[tid] += a;
        __syncthreads();
    }
    if (tid < NBUCK) { int e = s[tid] - v; colBase[tid] = e; colCur[tid] = e; }
    if (tid == NBUCK) colBase[NBUCK] = s[NBUCK];
}

__global__ __launch_bounds__(256) void k_scat_row(const int* __restrict__ ei,
                                                  int* __restrict__ rowCur,
                                                  uchar* __restrict__ rowScat) {
    __shared__ int h[NBUCK], lb[NBUCK], lc[NBUCK];
    int tid = threadIdx.x;
    for (int b = tid; b < NBUCK; b += 256) { h[b] = 0; lc[b] = 0; }
    __syncthreads();
    const int gstep = NB_HIST * 256;
    const int gt = blockIdx.x * 256 + tid;
    for (int e = gt; e < NE; e += gstep) atomicAdd(&h[ei[e] >> 8], 1);
    __syncthreads();
    for (int b = tid; b < NBUCK; b += 256)
        lb[b] = h[b] ? atomicAdd(&rowCur[b], h[b]) : 0;
    __syncthreads();
    for (int e = gt; e < NE; e += gstep) {
        int r = ei[e];
        int b = r >> 8;
        int pos = lb[b] + atomicAdd(&lc[b], 1);
        rowScat[pos] = (uchar)(r & 255);
    }
}

__global__ __launch_bounds__(1024) void k_deg(const uchar* __restrict__ rowScat,
                                              const int* __restrict__ rowBase,
                                              float* __restrict__ dinv) {
    __shared__ int h[256];
    int tid = threadIdx.x;
    int b = blockIdx.x;
    if (tid < 256) h[tid] = 0;
    __syncthreads();
    int base = rowBase[b], cnt = rowBase[b + 1] - base;
    for (int i = tid; i < cnt; i += 1024) atomicAdd(&h[rowScat[base + i]], 1);
    __syncthreads();
    if (tid < 256) {
        int node = b * 256 + tid;
        if (node < NN) dinv[node] = rsqrtf((float)h[tid] + 1.0f);
    }
}

// record: {norm, bf16(ea0)|bf16(ea1), bf16(ea2)|fine8, row}
__global__ __launch_bounds__(256) void k_scat_col(const int* __restrict__ ei,
                                                  const float* __restrict__ ea,
                                                  const float* __restrict__ dinv,
                                                  int* __restrict__ colCur,
                                                  uint4* __restrict__ tmp) {
    __shared__ int h[NBUCK], lb[NBUCK], lc[NBUCK];
    int tid = threadIdx.x;
    for (int b = tid; b < NBUCK; b += 256) { h[b] = 0; lc[b] = 0; }
    __syncthreads();
    const int gstep = NB_HIST * 256;
    const int gt = blockIdx.x * 256 + tid;
    for (int e = gt; e < NE; e += gstep) atomicAdd(&h[ei[NE + e] >> 8], 1);
    __syncthreads();
    for (int b = tid; b < NBUCK; b += 256)
        lb[b] = h[b] ? atomicAdd(&colCur[b], h[b]) : 0;
    __syncthreads();
    for (int e = gt; e < NE; e += gstep) {
        int r = ei[e];
        int c = ei[NE + e];
        int b = c >> 8;
        int pos = lb[b] + atomicAdd(&lc[b], 1);
        uint4 rec;
        rec.x = __float_as_uint(dinv[r] * dinv[c]);
        rec.y = ((uint)f2bf(ea[e * 3]) << 16) | (uint)f2bf(ea[e * 3 + 1]);
        rec.z = ((uint)f2bf(ea[e * 3 + 2]) << 16) | (uint)(c & 255);
        rec.w = (uint)r;
        tmp[pos] = rec;
    }
}

__global__ __launch_bounds__(1024) void k_sort_col(const uint4* __restrict__ tmp,
                                                   const int* __restrict__ colBase,
                                                   uint4* __restrict__ csr,
                                                   int* __restrict__ offs) {
    __shared__ int hh[256], sc[256], cur[256];
    int tid = threadIdx.x;
    int b = blockIdx.x;
    if (tid < 256) hh[tid] = 0;
    __syncthreads();
    int base = colBase[b], cnt = colBase[b + 1] - base;
    for (int i = tid; i < cnt; i += 1024) atomicAdd(&hh[tmp[base + i].z & 255], 1);
    __syncthreads();
    int v = 0;
    if (tid < 256) { v = hh[tid]; sc[tid] = v; }
    __syncthreads();
    for (int d = 1; d < 256; d <<= 1) {
        int add = 0;
        if (tid < 256 && tid >= d) add = sc[tid - d];
        __syncthreads();
        if (tid < 256) sc[tid] += add;
        __syncthreads();
    }
    if (tid < 256) {
        int excl = sc[tid] - v;
        int node = b * 256 + tid;
        if (node < NN) offs[node] = base + excl;
        if (b == NBUCK - 1 && tid == 0) offs[NN] = NE;
        cur[tid] = excl;
    }
    __syncthreads();
    for (int i = tid; i < cnt; i += 1024) {
        uint4 rec = tmp[base + i];
        int f = rec.z & 255;
        int pos = atomicAdd(&cur[f], 1);
        csr[base + pos] = rec;
    }
}

// ---------------- fused BN-fold + weight prep ----------------
// grid 256 x 128. Blocks 0..127: Wt row n (bf16, transposed, A-scaled).
// Blocks 128..255: beff col j. All blocks: zero a 64-elem slice of snext.
// Stats arrive as NREP replica slots (contention-free agg tail); A/B fold
// sums the replicas here (L2-resident, ~128 loads/thread).

__global__ __launch_bounds__(128) void k_prep(const float* __restrict__ W,
                                              const float* __restrict__ b,
                                              const float* __restrict__ g,
                                              const float* __restrict__ bt,
                                              const float* __restrict__ sprev,
                                              float* __restrict__ snext,
                                              int mode,
                                              ushort* __restrict__ Wt,
                                              float* __restrict__ beff) {
    __shared__ float s[DIM];
    int k = threadIdx.x;
    // zero next-layer stats replicas: 256 blocks x 64 elems = NREP*256
    if (k < 64) snext[blockIdx.x * 64 + k] = 0.0f;
    float A = 1.0f, B = 0.0f;
    if (mode) {
        float sm = 0.0f, sq = 0.0f;
        for (int r = 0; r < NREP; ++r) {
            sm += sprev[r * 256 + k];
            sq += sprev[r * 256 + 128 + k];
        }
        float m = sm * (1.0f / NN);
        float var = sq * (1.0f / NN) - m * m;
        float rs = rsqrtf(var + BN_EPS);
        A = rs * g[k];
        B = bt[k] - m * A;
    }
    if (blockIdx.x < DIM) {
        int n = blockIdx.x;
        Wt[n * DIM + k] = f2bf(A * W[k * DIM + n]);
    } else {
        int j = blockIdx.x - DIM;
        s[k] = B * W[k * DIM + j];
        __syncthreads();
        for (int d = 64; d > 0; d >>= 1) {
            if (k < d) s[k] += s[k + d];
            __syncthreads();
        }
        if (k == 0) beff[j] = b[j] + s[0];
    }
}

// ---------------- MFMA GEMM: Y[M,128] = A_bf[M,128] @ W + beff ----------------
// C/D: col = lane&15, row = quad*4 + reg  [measured: learn_hip m89/m91]

#define GEMM_MFMA_BODY(Abf, Wt)                                                     \
    const int lane = threadIdx.x & 63;                                              \
    const int wv   = threadIdx.x >> 6;                                              \
    const int m    = lane & 15;                                                     \
    const int quad = lane >> 4;                                                     \
    const int row0 = blockIdx.x * 64 + wv * 16;                                     \
    const int rr   = min(row0 + m, NN - 1);                                         \
    const short8* ap = (const short8*)&Abf[(size_t)rr * DIM + quad * 8];            \
    short8 a0 = ap[0];                                                              \
    short8 a1 = ap[4];                                                              \
    short8 a2 = ap[8];                                                              \
    short8 a3 = ap[12];                                                             \
    f32x4 acc[8];                                                                   \
    _Pragma("unroll")                                                               \
    for (int nt = 0; nt < 8; ++nt) {                                                \
        const short8* bp = (const short8*)&Wt[(size_t)(nt * 16 + m) * DIM + quad * 8]; \
        f32x4 c = {0.f, 0.f, 0.f, 0.f};                                             \
        c = __builtin_amdgcn_mfma_f32_16x16x32_bf16(a0, bp[0],  c, 0, 0, 0);        \
        c = __builtin_amdgcn_mfma_f32_16x16x32_bf16(a1, bp[4],  c, 0, 0, 0);        \
        c = __builtin_amdgcn_mfma_f32_16x16x32_bf16(a2, bp[8],  c, 0, 0, 0);        \
        c = __builtin_amdgcn_mfma_f32_16x16x32_bf16(a3, bp[12], c, 0, 0, 0);        \
        acc[nt] = c;                                                                \
    }                                                                               \
    const int rbase = row0 + quad * 4;

__global__ __launch_bounds__(256) void k_gemm_mf_bf(const ushort* __restrict__ Abf,
                                                    const ushort* __restrict__ Wt,
                                                    const float* __restrict__ beff,
                                                    ushort* __restrict__ Y) {
    GEMM_MFMA_BODY(Abf, Wt)
#pragma unroll
    for (int nt = 0; nt < 8; ++nt) {
        int col = nt * 16 + m;
        float bb = beff[col];
#pragma unroll
        for (int i = 0; i < 4; ++i) {
            int row = rbase + i;
            if (row < NN) Y[(size_t)row * DIM + col] = f2bf(acc[nt][i] + bb);
        }
    }
}

__global__ __launch_bounds__(256) void k_gemm_mf_f32(const ushort* __restrict__ Abf,
                                                     const ushort* __restrict__ Wt,
                                                     const float* __restrict__ beff,
                                                     float* __restrict__ Y) {
    GEMM_MFMA_BODY(Abf, Wt)
#pragma unroll
    for (int nt = 0; nt < 8; ++nt) {
        int col = nt * 16 + m;
        float bb = beff[col];
#pragma unroll
        for (int i = 0; i < 4; ++i) {
            int row = rbase + i;
            if (row < NN) Y[(size_t)row * DIM + col] = acc[nt][i] + bb;
        }
    }
}

// ---------------- aggregation + fused BN statistics ----------------
// wave processes 4 nodes; 8 edges/iter (lane = q*16 + oc, 4 edge-quads x 2).
// 2-deep software pipeline. BN partials merged per block in LDS, then one
// atomicAdd per thread into a REPLICA slot (blockIdx&63) -> ~98 RMWs/addr
// over 1024 cachelines (round-4's single-slot version was 6250 RMWs/addr
// on 16 cachelines = +84us serialized drain).

static __device__ __forceinline__ void edge_compute(float4 r, float4 hv, float n,
                                                    const v2f* __restrict__ w0,
                                                    const v2f* __restrict__ w1,
                                                    const v2f* __restrict__ w2,
                                                    const v2f* __restrict__ vbe,
                                                    v2f* __restrict__ acc) {
    uint py = __float_as_uint(r.y), pz = __float_as_uint(r.z);
    v2f va0 = vbc(bf_hi(py)), va1 = vbc(bf_lo(py)), va2 = vbc(bf_hi(pz));
    v2f vn = vbc(n);
    uint hx = __float_as_uint(hv.x), hy = __float_as_uint(hv.y);
    uint hz = __float_as_uint(hv.z), hw = __float_as_uint(hv.w);
    v2f hp[4] = {{bf_lo(hx), bf_hi(hx)}, {bf_lo(hy), bf_hi(hy)},
                 {bf_lo(hz), bf_hi(hz)}, {bf_lo(hw), bf_hi(hw)}};
    const v2f z = {0.0f, 0.0f};
#pragma unroll
    for (int j = 0; j < 4; ++j) {
        v2f e = vfma(va2, w2[j], vbe[j]);
        e = vfma(va1, w1[j], e);
        e = vfma(va0, w0[j], e);
        v2f u = hp[j] + e;
        u = __builtin_elementwise_max(u, z);   // v_pk_max_f32
        acc[j] = vfma(vn, u, acc[j]);
    }
}

__global__ __launch_bounds__(256) void k_agg(const float4* __restrict__ h4,
                                             const float4* __restrict__ csr,
                                             const int* __restrict__ offs,
                                             const float* __restrict__ We,
                                             const float* __restrict__ be,
                                             uint* __restrict__ tb,
                                             float* __restrict__ stats) {
    __shared__ float pbuf[4][256];
    int wv = threadIdx.x >> 6;
    int lane = threadIdx.x & 63;
    int q  = lane >> 4;
    int oc = lane & 15;
    int j0 = oc * 8;

    float4 t0, t1;
    t0 = *(const float4*)&We[j0];             t1 = *(const float4*)&We[j0 + 4];
    v2f w0[4] = {{t0.x, t0.y}, {t0.z, t0.w}, {t1.x, t1.y}, {t1.z, t1.w}};
    t0 = *(const float4*)&We[DIM + j0];       t1 = *(const float4*)&We[DIM + j0 + 4];
    v2f w1[4] = {{t0.x, t0.y}, {t0.z, t0.w}, {t1.x, t1.y}, {t1.z, t1.w}};
    t0 = *(const float4*)&We[2 * DIM + j0];   t1 = *(const float4*)&We[2 * DIM + j0 + 4];
    v2f w2[4] = {{t0.x, t0.y}, {t0.z, t0.w}, {t1.x, t1.y}, {t1.z, t1.w}};
    t0 = *(const float4*)&be[j0];             t1 = *(const float4*)&be[j0 + 4];
    v2f vbe[4] = {{t0.x, t0.y}, {t0.z, t0.w}, {t1.x, t1.y}, {t1.z, t1.w}};

    v2f smv[4] = {{0,0},{0,0},{0,0},{0,0}};
    v2f sqv[4] = {{0,0},{0,0},{0,0},{0,0}};

    const int v0 = blockIdx.x * 16 + wv * 4;     // NBLK_AGG*16 == NN exactly
    int ofs[5];
#pragma unroll
    for (int k = 0; k < 5; ++k) ofs[k] = offs[v0 + k];

    for (int it = 0; it < 4; ++it) {
        int v = v0 + it;
        v2f acc[4] = {{0,0},{0,0},{0,0},{0,0}};
        int s0 = ofs[it], e0 = ofs[it + 1];

        // pipeline prologue: issue csr for iter0 AND iter1 together, then
        // h gathers for iter0 (rA wait is the only exposed latency per node)
        float4 rA1 = csr[s0 + q];
        float4 rA2 = csr[s0 + 4 + q];
        float4 rB1 = csr[s0 + 8 + q];
        float4 rB2 = csr[s0 + 12 + q];
        float4 hA1 = h4[(size_t)__float_as_int(rA1.w) * 16 + oc];
        float4 hA2 = h4[(size_t)__float_as_int(rA2.w) * 16 + oc];

#pragma unroll 2
        for (int base = s0; base < e0; base += 8) {
            // stage B: rows -> issue h(B); issue csr(C)
            float4 hB1 = h4[(size_t)__float_as_int(rB1.w) * 16 + oc];
            float4 hB2 = h4[(size_t)__float_as_int(rB2.w) * 16 + oc];
            float4 rC1 = csr[base + 16 + q];
            float4 rC2 = csr[base + 20 + q];
            // stage A compute (hA issued one iteration ago)
            float n1 = (base + q < e0) ? rA1.x : 0.0f;
            float n2 = (base + 4 + q < e0) ? rA2.x : 0.0f;
            edge_compute(rA1, hA1, n1, w0, w1, w2, vbe, acc);
            edge_compute(rA2, hA2, n2, w0, w1, w2, vbe, acc);
            rA1 = rB1; rA2 = rB2; rB1 = rC1; rB2 = rC2;
            hA1 = hB1; hA2 = hB2;
        }

        // reduce across the 4 edge-quads (lanes with equal oc)
#pragma unroll
        for (int j = 0; j < 4; ++j) {
            acc[j].x += __shfl_xor(acc[j].x, 16); acc[j].x += __shfl_xor(acc[j].x, 32);
            acc[j].y += __shfl_xor(acc[j].y, 16); acc[j].y += __shfl_xor(acc[j].y, 32);
        }

        if (q == 0) {
            uint4 pk;
            uint pw[4];
#pragma unroll
            for (int j = 0; j < 4; ++j) {
                acc[j].x = fmaxf(acc[j].x, 0.0f);   // outer relu
                acc[j].y = fmaxf(acc[j].y, 0.0f);
                smv[j] = smv[j] + acc[j];
                sqv[j] = vfma(acc[j], acc[j], sqv[j]);
                pw[j] = ((uint)f2bf(acc[j].y) << 16) | f2bf(acc[j].x);
            }
            pk.x = pw[0]; pk.y = pw[1]; pk.z = pw[2]; pk.w = pw[3];
            *(uint4*)&tb[(size_t)v * 64 + oc * 4] = pk;
        }
    }

    if (q == 0) {
#pragma unroll
        for (int j = 0; j < 4; ++j) {
            pbuf[wv][j0 + 2 * j]       = smv[j].x;
            pbuf[wv][j0 + 2 * j + 1]   = smv[j].y;
            pbuf[wv][128 + j0 + 2 * j]     = sqv[j].x;
            pbuf[wv][128 + j0 + 2 * j + 1] = sqv[j].y;
        }
    }
    __syncthreads();
    int tid = threadIdx.x;
    float s = pbuf[0][tid] + pbuf[1][tid] + pbuf[2][tid] + pbuf[3][tid];
    atomicAdd(&stats[(blockIdx.x & (NREP - 1)) * 256 + tid], s);
}

// ---------------- launch ----------------

static inline char* alignp(char* p, size_t a) {
    return (char*)(((uintptr_t)p + a - 1) & ~(uintptr_t)(a - 1));
}

extern "C" void kernel_launch(void* const* d_in, const int* in_sizes, int n_in,
                              void* d_out, int out_size, void* d_ws, size_t ws_size,
                              hipStream_t stream) {
    const float* x   = (const float*)d_in[0];
    const int*   ei  = (const int*)d_in[1];
    const float* ea  = (const float*)d_in[2];
    const float* Wp[3]  = {(const float*)d_in[3],  (const float*)d_in[9],  (const float*)d_in[15]};
    const float* bp[3]  = {(const float*)d_in[4],  (const float*)d_in[10], (const float*)d_in[16]};
    const float* Wep[3] = {(const float*)d_in[5],  (const float*)d_in[11], (const float*)d_in[17]};
    const float* bep[3] = {(const float*)d_in[6],  (const float*)d_in[12], (const float*)d_in[18]};
    const float* gp[3]  = {(const float*)d_in[7],  (const float*)d_in[13], (const float*)d_in[19]};
    const float* btp[3] = {(const float*)d_in[8],  (const float*)d_in[14], (const float*)d_in[20]};
    const float* Wl  = (const float*)d_in[21];
    const float* bl  = (const float*)d_in[22];
    float* out = (float*)d_out;

    char* p = (char*)d_ws;
    auto alloc = [&](size_t bytes) -> void* {
        p = alignp(p, 256);
        void* r = (void*)p;
        p += bytes;
        return r;
    };

    int*    bcnt     = (int*)alloc(2 * NBUCK * sizeof(int));
    int*    rowCnt   = bcnt;
    int*    colCnt   = bcnt + NBUCK;
    int*    rowBase  = (int*)alloc((NBUCK + 1) * sizeof(int));
    int*    colBase  = (int*)alloc((NBUCK + 1) * sizeof(int));
    int*    rowCur   = (int*)alloc(NBUCK * sizeof(int));
    int*    colCur   = (int*)alloc(NBUCK * sizeof(int));
    int*    offs     = (int*)alloc((NN + 1) * sizeof(int));
    float*  dinv     = (float*)alloc(NN * sizeof(float));
    uchar*  rowScat  = (uchar*)alloc(NE * sizeof(uchar));
    uint4*  csr      = (uint4*)alloc(((size_t)NE + CSR_PAD) * sizeof(uint4));
    ushort* x_bf     = (ushort*)alloc((size_t)NN * DIM * sizeof(ushort));
    ushort* h_bf     = (ushort*)alloc((size_t)NN * DIM * sizeof(ushort));
    ushort* t_bf     = (ushort*)alloc((size_t)NN * DIM * sizeof(ushort));
    ushort* Wt       = (ushort*)alloc(DIM * DIM * sizeof(ushort));
    float*  beff     = (float*)alloc(DIM * sizeof(float));
    float*  sb0      = (float*)alloc((size_t)NREP * 256 * sizeof(float));
    float*  sb1      = (float*)alloc((size_t)NREP * 256 * sizeof(float));

    // tmp (bucket-scattered records) aliases t_bf: both 25.6 MB; tmp dies at
    // k_sort_col, t_bf is first written by layer-1 k_agg (strictly later).
    uint4* tmp = (uint4*)t_bf;

    hipMemsetAsync(bcnt, 0, 2 * NBUCK * sizeof(int), stream);
    hipMemsetAsync(csr + NE, 0, CSR_PAD * sizeof(uint4), stream);  // zero-norm pad
    k_count<<<NB_HIST, 256, 0, stream>>>(ei, x, rowCnt, colCnt, x_bf);
    k_scanb<<<1, 512, 0, stream>>>(rowCnt, colCnt, rowBase, colBase, rowCur, colCur);
    k_scat_row<<<NB_HIST, 256, 0, stream>>>(ei, rowCur, rowScat);
    k_deg<<<NBUCK, 1024, 0, stream>>>(rowScat, rowBase, dinv);
    k_scat_col<<<NB_HIST, 256, 0, stream>>>(ei, ea, dinv, colCur, tmp);
    k_sort_col<<<NBUCK, 1024, 0, stream>>>(tmp, colBase, csr, offs);

    // stats double-buffer: scur(l) = (l&1)? sb1 : sb0; sprev(l) = the other.
    float* sbs[2] = {sb0, sb1};
    const ushort* Xbf = x_bf;
    for (int l = 0; l < 3; ++l) {
        float* scur = sbs[l & 1];
        float* sprev = sbs[(l + 1) & 1];
        const float* gg = (l == 0) ? gp[0] : gp[l - 1];
        const float* bb = (l == 0) ? btp[0] : btp[l - 1];
        k_prep<<<256, 128, 0, stream>>>(Wp[l], bp[l], gg, bb, sprev, scur,
                                        (l == 0) ? 0 : 1, Wt, beff);
        k_gemm_mf_bf<<<NBLK_GEMM, 256, 0, stream>>>(Xbf, Wt, beff, h_bf);
        k_agg<<<NBLK_AGG, 256, 0, stream>>>((const float4*)h_bf, (const float4*)csr, offs,
                                            Wep[l], bep[l], (uint*)t_bf, scur);
        Xbf = t_bf;
    }

    // final linear: BN3 folded (stats in scur(2) = sb0)
    k_prep<<<256, 128, 0, stream>>>(Wl, bl, gp[2], btp[2], sb0, sb1, 1, Wt, beff);
    k_gemm_mf_f32<<<NBLK_GEMM, 256, 0, stream>>>(t_bf, Wt, beff, out);
}